// Round 4
// baseline (8769.121 us; speedup 1.0000x reference)
//
#include <hip/hip_runtime.h>

typedef unsigned int u32;
typedef unsigned short u16;

constexpr int NIN = 10, H = 100, OUTN = 10, NL = 5, NB = 64, T = 2048;

__device__ __forceinline__ float b2f(u16 u){ return __builtin_bit_cast(float, ((u32)u)<<16); }
__device__ __forceinline__ u32 f2bu(float f){
  u32 u = __builtin_bit_cast(u32, f);
  return (u + 0x7fffu + ((u>>16)&1u)) >> 16;  // RNE bf16 (output fallback only)
}
__device__ __forceinline__ float ftanh(float x){
  float e = __expf(x + x);
  return 1.0f - 2.0f/(e + 1.0f);
}

// Two blocks per batch row (grid 128): block b = layers 0..2, block b+64 =
// layers 3..4 + out. Full fp32 everywhere (recurrent noise amplification
// saturates any fp16/bf16 internal state at ~5e-2 absmax — rounds 2/3).
// Each matvec role = wave-pair, 1 row/lane, 100 fp32 weights in VGPRs;
// h broadcast from LDS as float4. h2 crosses blocks via a ring in d_ws with
// agent-scope release/acquire; 0xAA ws-poison (negative int) = "not ready".
__global__ __launch_bounds__(640, 1)
void rnn5(const void* __restrict__ xg, const void* __restrict__ hprev,
          const void* __restrict__ Wih0, const void* __restrict__ Wih,
          const void* __restrict__ Whh, const void* __restrict__ bih,
          const void* __restrict__ bhh, const void* __restrict__ Wout,
          const void* __restrict__ bout, void* __restrict__ outv,
          float* __restrict__ ring, int* __restrict__ flags, int ringSlots)
{
  __shared__ __align__(16) float hb[3][2][128];   // A: h0,h1,h2 ; B: h3,h4
  __shared__ __align__(16) float part[2][128];    // ih partials
  __shared__ __align__(16) float h2l[2][112];     // B: staged h2
  __shared__ __align__(16) float xst[2][12];      // A: staged x[t] (pad 12)

  const int tid = threadIdx.x, wv = tid>>6, lane = tid&63;
  const bool isA = (blockIdx.x < NB);
  const int b = isA ? (int)blockIdx.x : (int)blockIdx.x - NB;
  const int rmask = ringSlots - 1;
  int* progp = flags + b*32;            // h2 ready-count (A publishes)
  int* consp = flags + NB*32 + b*32;    // h2 consumed-count (B publishes)

  // runtime storage-dtype detection (proved fp32 in r1->r2, kept for safety)
  bool isf32 = false;
  { const u16* p = (const u16*)Wih0;
    for (int i=0;i<128;++i) if (((p[i]>>7)&0xFF) >= 0x80) isf32 = true; }
  auto ldf = [&](const void* p, size_t i)->float {
    return isf32 ? ((const float*)p)[i] : b2f(((const u16*)p)[i]); };

  // ---- per-wave role setup -------------------------------------------------
  float w[100];
  #pragma unroll
  for (int i=0;i<100;++i) w[i]=0.f;
  float wx[12];
  #pragma unroll
  for (int i=0;i<12;++i) wx[i]=0.f;
  float bias = 0.f;
  int dt = 1<<20, srcL = 0, partIdx = -1, dstL = 0;
  bool srcH2=false, hh=false, hasX=false, ringSt=false, isOut=false;
  const int row = ((wv&1)?64:0) + lane;

  if (isA){
    if (wv<2){            // L0 hh + x
      dt=0; hh=true; dstL=0; srcL=0; hasX=true;
      if (row<H){
        for (int k=0;k<H;++k) w[k]=ldf(Whh,(size_t)row*H+k);
        for (int d=0;d<NIN;++d) wx[d]=ldf(Wih0,(size_t)row*NIN+d);
        bias = ldf(bih,row)+ldf(bhh,row);
      }
    } else if (wv<4){     // L1 ih (Wih[0])
      dt=1; srcL=0; partIdx=0;
      if (row<H) for (int k=0;k<H;++k) w[k]=ldf(Wih,(size_t)row*H+k);
    } else if (wv<6){     // L1 hh
      dt=1; hh=true; dstL=1; srcL=1; partIdx=0;
      if (row<H){
        for (int k=0;k<H;++k) w[k]=ldf(Whh,(size_t)1*H*H+(size_t)row*H+k);
        bias = ldf(bih,1*H+row)+ldf(bhh,1*H+row);
      }
    } else if (wv<8){     // L2 ih (Wih[1])
      dt=2; srcL=1; partIdx=1;
      if (row<H) for (int k=0;k<H;++k) w[k]=ldf(Wih,(size_t)1*H*H+(size_t)row*H+k);
    } else {              // L2 hh + ring store
      dt=2; hh=true; dstL=2; srcL=2; partIdx=1; ringSt=true;
      if (row<H){
        for (int k=0;k<H;++k) w[k]=ldf(Whh,(size_t)2*H*H+(size_t)row*H+k);
        bias = ldf(bih,2*H+row)+ldf(bhh,2*H+row);
      }
    }
  } else {
    if (wv<2){            // L3 ih (Wih[2], src = staged h2)
      dt=0; srcH2=true; partIdx=0;
      if (row<H) for (int k=0;k<H;++k) w[k]=ldf(Wih,(size_t)2*H*H+(size_t)row*H+k);
    } else if (wv<4){     // L3 hh
      dt=0; hh=true; dstL=0; srcL=0; partIdx=0;
      if (row<H){
        for (int k=0;k<H;++k) w[k]=ldf(Whh,(size_t)3*H*H+(size_t)row*H+k);
        bias = ldf(bih,3*H+row)+ldf(bhh,3*H+row);
      }
    } else if (wv<6){     // L4 ih (Wih[3])
      dt=1; srcL=0; partIdx=1;
      if (row<H) for (int k=0;k<H;++k) w[k]=ldf(Wih,(size_t)3*H*H+(size_t)row*H+k);
    } else if (wv<8){     // L4 hh
      dt=1; hh=true; dstL=1; srcL=1; partIdx=1;
      if (row<H){
        for (int k=0;k<H;++k) w[k]=ldf(Whh,(size_t)4*H*H+(size_t)row*H+k);
        bias = ldf(bih,4*H+row)+ldf(bhh,4*H+row);
      }
    } else if (wv==8){    // out projection
      dt=2; isOut=true; srcL=1;
      if (lane<OUTN){
        for (int k=0;k<H;++k) w[k]=ldf(Wout,(size_t)lane*H+k);
        bias = ldf(bout,lane);
      }
    }                      // wv9: idle (dt huge)
  }

  // ---- LDS init ------------------------------------------------------------
  if (tid < 3*128){
    int l = tid>>7, r = tid&127;
    bool use = isA ? true : (l<2);
    if (use){
      int gl = isA ? l : (l+3);
      float v = 0.f;
      if (r<H) v = ldf(hprev, ((size_t)gl*NB+b)*H + r);
      hb[l][1][r] = v;  hb[l][0][r] = 0.f;
    }
  }
  if (isA && wv==0){
    if (lane<NIN){
      size_t x0 = (size_t)b*T*NIN;
      xst[0][lane] = ldf(xg, x0+lane);
      xst[1][lane] = ldf(xg, x0+NIN+lane);
    } else if (lane<12){
      xst[0][lane]=0.f; xst[1][lane]=0.f;
    }
  }
  if (!isA && wv==8){     // pre-stage h2[0]
    while (__hip_atomic_load(progp, __ATOMIC_ACQUIRE, __HIP_MEMORY_SCOPE_AGENT) < 1)
      __builtin_amdgcn_s_sleep(2);
    if (lane<28){
      size_t base = (size_t)(b*ringSlots)*112;
      ((float4*)h2l[0])[lane] = ((const float4*)(ring+base))[lane];
    }
    if (lane==0)
      __hip_atomic_store(consp, 1, __ATOMIC_RELEASE, __HIP_MEMORY_SCOPE_AGENT);
  }
  __syncthreads();

  // ---- main pipelined loop -------------------------------------------------
  float yreg[8];
  #pragma unroll
  for (int i=0;i<8;++i) yreg[i]=0.f;
  const size_t yBase  = (size_t)b*T*OUTN;
  const size_t hfBase = (size_t)NB*T*OUTN;
  float* outf = (float*)outv;  u16* outh = (u16*)outv;
  float xr = 0.f;

  for (int s=0; s<=T+1; ++s){
    const int t = s - dt;
    const bool act = (t>=0) && (t<T);
    float a = 0.f;

    if (isA && wv==0){                       // backpressure + publish
      int t2 = s-2;
      if (t2 >= ringSlots){
        while (__hip_atomic_load(consp, __ATOMIC_ACQUIRE, __HIP_MEMORY_SCOPE_AGENT)
               < t2 - ringSlots + 1)
          __builtin_amdgcn_s_sleep(2);
      }
      if (s>=3 && lane==0)
        __hip_atomic_store(progp, s-2, __ATOMIC_RELEASE, __HIP_MEMORY_SCOPE_AGENT);
    }

    if (act){
      const int slot = hh ? ((t&1)^1) : (t&1);
      const float* hsrc = srcH2 ? h2l[slot] : hb[srcL][slot];
      const float4* h4p = (const float4*)hsrc;
      float a0=bias, a1=0.f, a2=0.f, a3=0.f;
      #pragma unroll
      for (int c=0;c<25;++c){
        float4 hv = h4p[c];                  // broadcast ds_read_b128
        a0 = __builtin_fmaf(w[4*c+0], hv.x, a0);
        a1 = __builtin_fmaf(w[4*c+1], hv.y, a1);
        a2 = __builtin_fmaf(w[4*c+2], hv.z, a2);
        a3 = __builtin_fmaf(w[4*c+3], hv.w, a3);
      }
      if (hasX){
        const float4* xp4 = (const float4*)xst[t&1];
        #pragma unroll
        for (int c=0;c<3;++c){
          float4 xv = xp4[c];
          a0 = __builtin_fmaf(wx[4*c+0], xv.x, a0);
          a1 = __builtin_fmaf(wx[4*c+1], xv.y, a1);
          a2 = __builtin_fmaf(wx[4*c+2], xv.z, a2);
          a3 = __builtin_fmaf(wx[4*c+3], xv.w, a3);
        }
      }
      a = (a0+a1)+(a2+a3);
      if (partIdx>=0 && !hh) part[partIdx][row] = a;
    }

    if (!isA && wv==8 && (s+1)<T){           // poll + stage h2[s+1]
      while (__hip_atomic_load(progp, __ATOMIC_ACQUIRE, __HIP_MEMORY_SCOPE_AGENT) < s+2)
        __builtin_amdgcn_s_sleep(2);
      if (lane<28){
        size_t base = (size_t)(b*ringSlots + ((s+1)&rmask))*112;
        ((float4*)h2l[(s+1)&1])[lane] = ((const float4*)(ring+base))[lane];
      }
      if (lane==0)
        __hip_atomic_store(consp, s+2, __ATOMIC_RELEASE, __HIP_MEMORY_SCOPE_AGENT);
    }
    if (isA && wv==0 && lane<NIN && (s+2)<T){ // x prefetch (2-step lookahead)
      size_t xi = (size_t)b*T*NIN + (size_t)(s+2)*NIN + lane;
      xr = isf32 ? ((const float*)xg)[xi] : b2f(((const u16*)xg)[xi]);
    }
    __syncthreads();

    // phase B: finalize / output
    if (act && hh){
      float v = a;
      if (partIdx>=0) v += part[partIdx][row];
      float hval = ftanh(v);
      hb[dstL][t&1][row] = hval;
      if (ringSt && row<H)
        ring[(size_t)(b*ringSlots + (t&rmask))*112 + row] = hval;
      if (t==T-1 && row<H){
        int gl = isA ? dstL : dstL+3;
        size_t o = hfBase + ((size_t)gl*NB + b)*H + row;
        if (isf32) outf[o]=hval; else outh[o]=(u16)f2bu(hval);
      }
    }
    if (isOut && act && lane<OUTN){
      yreg[t&7] = a;
      if ((t&7)==7){
        size_t basei = yBase + (size_t)(t-7)*OUTN + lane;
        if (isf32){
          #pragma unroll
          for (int q=0;q<8;++q) outf[basei+(size_t)q*OUTN] = yreg[q];
        } else {
          #pragma unroll
          for (int q=0;q<8;++q) outh[basei+(size_t)q*OUTN] = (u16)f2bu(yreg[q]);
        }
      }
    }
    if (isA && wv==0 && lane<NIN && (s+2)<T)
      xst[s&1][lane] = xr;                   // slot s&1 == (s+2)&1
    __syncthreads();
  }
  if (isA && wv==0 && lane==0)
    __hip_atomic_store(progp, T, __ATOMIC_RELEASE, __HIP_MEMORY_SCOPE_AGENT);
}

extern "C" void kernel_launch(void* const* d_in, const int* in_sizes, int n_in,
                              void* d_out, int out_size, void* d_ws, size_t ws_size,
                              hipStream_t stream){
  int* flags = (int*)d_ws;                       // 2*64*32 ints = 16 KB, 0xAA-poisoned => negative
  size_t flagBytes = (size_t)2*NB*32*sizeof(int);
  float* ring = (float*)((char*)d_ws + flagBytes);
  size_t availF = ws_size > flagBytes ? (ws_size - flagBytes)/sizeof(float) : 0;
  int slots = 64;
  while (slots > 2 && (size_t)NB*slots*112 > availF) slots >>= 1;
  rnn5<<<dim3(2*NB), dim3(640), 0, stream>>>(
    d_in[0], d_in[1], d_in[2], d_in[3], d_in[4],
    d_in[5], d_in[6], d_in[7], d_in[8], d_out,
    ring, flags, slots);
}